// Round 16
// baseline (40.170 us; speedup 1.0000x reference)
//
#include <hip/hip_runtime.h>

typedef __attribute__((ext_vector_type(8))) short short8;
typedef __attribute__((ext_vector_type(16))) float f32x16;
typedef __attribute__((ext_vector_type(2))) float f32x2;
typedef __attribute__((ext_vector_type(2))) unsigned int uint2v;

#define HW 1026
#define CH_STRIDE (HW * HW)           /* 1052676 */
#define TW 32                         /* output cols per block */
#define ROW_BYTES 1088                /* 34 px * 16ch * 2B     */
#define X_ROWS 18
#define X_LDS (X_ROWS * ROW_BYTES)    /* 19584 */
#define W_LDS (9 * 32 * 16 * 2)       /* 9216: [rs][o][c] bf16 */
#define T_TILES 4                     /* 64 output rows per block */

__device__ __forceinline__ unsigned short f2bf(float f) {
    unsigned int u = __builtin_bit_cast(unsigned int, f);
    u += 0x7fffu + ((u >> 16) & 1u);
    return (unsigned short)(u >> 16);
}

// stage NROWS x-rows (xrow0..) into phys rows (ro..ro+NROWS-1) mod 18.
// R15's proven chunked issue/convert pattern; ro is wave-uniform (SGPR).
template<int NROWS>
__device__ __forceinline__ void stage_tile(const float* __restrict__ x, int xrow0, int w0,
                                           int tid, unsigned char* __restrict__ buf, int ro) {
    constexpr int UNITS = 4 * NROWS * 17;
    f32x2 vA[4][4], vB[4];
    #pragma unroll
    for (int k = 0; k < 4; ++k) {                   // issue rounds 0..3
        const int idx = tid + k * 256;
        if (idx < UNITS) {
            const int c4  = idx / (NROWS * 17);
            const int rem = idx - c4 * (NROWS * 17);
            const int row = rem / 17;
            const int u   = rem - row * 17;
            const float* base = x + (4 * c4) * CH_STRIDE + (xrow0 + row) * HW + (w0 + 2 * u);
            #pragma unroll
            for (int j = 0; j < 4; ++j)
                vA[k][j] = *(const f32x2*)(base + j * CH_STRIDE);
        }
    }
    {                                               // issue round 4
        const int idx = tid + 4 * 256;
        if (idx < UNITS) {
            const int c4  = idx / (NROWS * 17);
            const int rem = idx - c4 * (NROWS * 17);
            const int row = rem / 17;
            const int u   = rem - row * 17;
            const float* base = x + (4 * c4) * CH_STRIDE + (xrow0 + row) * HW + (w0 + 2 * u);
            #pragma unroll
            for (int j = 0; j < 4; ++j)
                vB[j] = *(const f32x2*)(base + j * CH_STRIDE);
        }
    }
    #pragma unroll
    for (int k = 0; k < 5; ++k) {                   // convert + ds_write
        const int idx = tid + k * 256;
        if (idx < UNITS) {
            const int c4  = idx / (NROWS * 17);
            const int rem = idx - c4 * (NROWS * 17);
            const int row = rem / 17;
            const int u   = rem - row * 17;
            int phys = ro + row;
            if (phys >= X_ROWS) phys -= X_ROWS;
            #pragma unroll
            for (int p = 0; p < 2; ++p) {
                const int pp = 2 * u + p;
                const f32x2 q0 = (k < 4) ? vA[k & 3][0] : vB[0];
                const f32x2 q1 = (k < 4) ? vA[k & 3][1] : vB[1];
                const f32x2 q2 = (k < 4) ? vA[k & 3][2] : vB[2];
                const f32x2 q3 = (k < 4) ? vA[k & 3][3] : vB[3];
                const unsigned int lo  = (unsigned int)f2bf(q0[p]) |
                                         ((unsigned int)f2bf(q1[p]) << 16);
                const unsigned int hi2 = (unsigned int)f2bf(q2[p]) |
                                         ((unsigned int)f2bf(q3[p]) << 16);
                const int s16 = ((c4 >> 1) ^ (pp >> 2) ^ (pp >> 3)) & 1;
                const int off = phys * ROW_BYTES + pp * 32 + s16 * 16 + (c4 & 1) * 8;
                uint2v t; t.x = lo; t.y = hi2;
                *(uint2v*)(buf + off) = t;
            }
        }
    }
}

// compute 16 output rows hout..hout+15; x-row phys = (base + baserow + r) mod 18.
// af re-read from s_w per call: zero weight regs live during staging phases.
__device__ __forceinline__ void compute_store(const unsigned char* __restrict__ s_x,
                                              const unsigned char* __restrict__ s_w,
                                              float* __restrict__ out,
                                              int hout, int w0, int wv, int n, int hi,
                                              int base) {
    short8 af[9];
    #pragma unroll
    for (int rs = 0; rs < 9; ++rs)
        af[rs] = *(const short8*)(s_w + rs * 1024 + n * 32 + hi * 16);

    #pragma unroll
    for (int t = 0; t < 4; ++t) {
        const int baserow = wv * 4 + t;
        f32x16 acc;
        #pragma unroll
        for (int q = 0; q < 16; ++q) acc[q] = 0.0f;
        #pragma unroll
        for (int r = 0; r < 3; ++r) {
            int rr = base + baserow + r;             // uniform base: scalar wrap
            if (rr >= X_ROWS) rr -= X_ROWS;
            #pragma unroll
            for (int s = 0; s < 3; ++s) {
                const int w   = n + s;
                const int s16 = (hi ^ (w >> 2) ^ (w >> 3)) & 1;
                const int off = rr * ROW_BYTES + w * 32 + s16 * 16;
                const short8 bfr = *(const short8*)(s_x + off);   // ds_read_b128
                acc = __builtin_amdgcn_mfma_f32_32x32x16_bf16(af[r * 3 + s], bfr, acc, 0, 0, 0);
            }
        }
        // C/D: col(lane&31)=pixel, row(q)=(q&3)+8*(q>>2)+4*hi = outch; plain stores
        const int h = hout + baserow;
        float* obase = out + (h << 10) + w0 + n;
        #pragma unroll
        for (int q = 0; q < 16; ++q) {
            const int o = (q & 3) + 8 * (q >> 2) + 4 * hi;
            obase[o << 20] = acc[q];
        }
    }
}

__global__ __launch_bounds__(256, 2)
void gck3x3_mfma_kernel(const float* __restrict__ x,
                        const float* __restrict__ kern,
                        float* __restrict__ out) {
    __shared__ __attribute__((aligned(16))) unsigned char s_mem[X_LDS + W_LDS];
    unsigned char* s_x = s_mem;
    unsigned char* s_w = s_mem + X_LDS;

    const int tid  = threadIdx.x;
    const int lane = tid & 63;
    const int wv   = tid >> 6;
    const int n    = lane & 31;
    const int hi   = lane >> 5;

    // XCD-aware bijective swizzle: 512 = 8*64; vertical neighbors share an XCD L2
    const int bid = blockIdx.x;
    const int swz = (bid & 7) * 64 + (bid >> 3);
    const int h0  = (swz >> 5) * (16 * T_TILES);  // 0..960 (block owns 64 rows)
    const int w0  = (swz & 31) * TW;              // 0..992

    // ---- prologue: x rows h0..h0+17 -> phys 0..17; weights -> s_w ----
    stage_tile<18>(x, h0, w0, tid, s_x, 0);
    {
        float wreg[18];
        #pragma unroll
        for (int k = 0; k < 18; ++k)
            wreg[k] = kern[tid + 256 * k];
        #pragma unroll
        for (int k = 0; k < 18; ++k) {
            const int idx = tid + 256 * k;
            const int o   = idx / 144;
            const int rm  = idx - o * 144;
            const int c   = rm / 9;
            const int rs  = rm - c * 9;
            *(short*)(s_w + rs * 1024 + o * 32 + c * 2) = (short)f2bf(wreg[k]);
        }
    }
    __syncthreads();

    // ---- 4-tile rotating pipeline: stage j+1 overlaps store drain of j ----
    int base = 0;            // phys row of x-row (hout)   = (16*j) % 18
    int ro   = 0;            // phys row of next stage row = (16*(j+1)+2) % 18
    int hout = h0;
    int xr   = h0 + 18;
    #pragma unroll 1
    for (int j = 0; j < T_TILES; ++j) {
        compute_store(s_x, s_w, out, hout, w0, wv, n, hi, base);
        if (j + 1 < T_TILES) {
            __syncthreads();                         // all reads of old rows done
            stage_tile<16>(x, xr, w0, tid, s_x, ro); // reads overlap posted stores
            __syncthreads();
            xr += 16;
            ro   = (ro + 16 >= X_ROWS) ? ro - 2 : ro + 16;      // +16 mod 18
            base = (base + 16 >= X_ROWS) ? base - 2 : base + 16;
            hout += 16;
        }
    }
}

extern "C" void kernel_launch(void* const* d_in, const int* in_sizes, int n_in,
                              void* d_out, int out_size, void* d_ws, size_t ws_size,
                              hipStream_t stream) {
    (void)in_sizes; (void)n_in; (void)d_ws; (void)ws_size; (void)out_size;
    const float* x    = (const float*)d_in[0];
    const float* kern = (const float*)d_in[1];
    float*       out  = (float*)d_out;
    gck3x3_mfma_kernel<<<512, 256, 0, stream>>>(x, kern, out);
}

// Round 17
// 36.782 us; speedup vs baseline: 1.0921x; 1.0921x over previous
//
#include <hip/hip_runtime.h>

typedef __attribute__((ext_vector_type(8))) short short8;
typedef __attribute__((ext_vector_type(16))) float f32x16;
typedef __attribute__((ext_vector_type(2))) float f32x2;
typedef __attribute__((ext_vector_type(2))) unsigned int uint2v;

#define HW 1026
#define CH_STRIDE (HW * HW)           /* 1052676 */
#define TW 32                         /* output cols per block */
#define ROW_BYTES 1088                /* 34 px * 16ch * 2B     */
#define X_ROWS 18
#define X_LDS (X_ROWS * ROW_BYTES)    /* 19584 */
#define W_LDS (9 * 32 * 16 * 2)       /* 9216: [rs][o][c] bf16 */

__device__ __forceinline__ unsigned short f2bf(float f) {
    unsigned int u = __builtin_bit_cast(unsigned int, f);
    u += 0x7fffu + ((u >> 16) & 1u);
    return (unsigned short)(u >> 16);
}

// stage NROWS x-rows (xrow0..xrow0+NROWS-1) into phys rows 0..NROWS-1.
// chunked issue/convert pattern: peak ~40 staging regs, nothing else live.
template<int NROWS>
__device__ __forceinline__ void stage_tile(const float* __restrict__ x, int xrow0, int w0,
                                           int tid, unsigned char* __restrict__ buf) {
    constexpr int UNITS = 4 * NROWS * 17;
    f32x2 vA[4][4], vB[4];
    #pragma unroll
    for (int k = 0; k < 4; ++k) {                   // issue rounds 0..3
        const int idx = tid + k * 256;
        if (idx < UNITS) {
            const int c4  = idx / (NROWS * 17);
            const int rem = idx - c4 * (NROWS * 17);
            const int row = rem / 17;
            const int u   = rem - row * 17;
            const float* base = x + (4 * c4) * CH_STRIDE + (xrow0 + row) * HW + (w0 + 2 * u);
            #pragma unroll
            for (int j = 0; j < 4; ++j)
                vA[k][j] = *(const f32x2*)(base + j * CH_STRIDE);
        }
    }
    {                                               // issue round 4
        const int idx = tid + 4 * 256;
        if (idx < UNITS) {
            const int c4  = idx / (NROWS * 17);
            const int rem = idx - c4 * (NROWS * 17);
            const int row = rem / 17;
            const int u   = rem - row * 17;
            const float* base = x + (4 * c4) * CH_STRIDE + (xrow0 + row) * HW + (w0 + 2 * u);
            #pragma unroll
            for (int j = 0; j < 4; ++j)
                vB[j] = *(const f32x2*)(base + j * CH_STRIDE);
        }
    }
    #pragma unroll
    for (int k = 0; k < 5; ++k) {                   // convert + ds_write
        const int idx = tid + k * 256;
        if (idx < UNITS) {
            const int c4  = idx / (NROWS * 17);
            const int rem = idx - c4 * (NROWS * 17);
            const int row = rem / 17;
            const int u   = rem - row * 17;
            #pragma unroll
            for (int p = 0; p < 2; ++p) {
                const int pp = 2 * u + p;
                const f32x2 q0 = (k < 4) ? vA[k & 3][0] : vB[0];
                const f32x2 q1 = (k < 4) ? vA[k & 3][1] : vB[1];
                const f32x2 q2 = (k < 4) ? vA[k & 3][2] : vB[2];
                const f32x2 q3 = (k < 4) ? vA[k & 3][3] : vB[3];
                const unsigned int lo  = (unsigned int)f2bf(q0[p]) |
                                         ((unsigned int)f2bf(q1[p]) << 16);
                const unsigned int hi2 = (unsigned int)f2bf(q2[p]) |
                                         ((unsigned int)f2bf(q3[p]) << 16);
                const int s16 = ((c4 >> 1) ^ (pp >> 2) ^ (pp >> 3)) & 1;
                const int off = row * ROW_BYTES + pp * 32 + s16 * 16 + (c4 & 1) * 8;
                uint2v t; t.x = lo; t.y = hi2;
                *(uint2v*)(buf + off) = t;
            }
        }
    }
}

// compute 16 output rows (h0+BASE .. +BASE+15); x-row (BASE+baserow+r) wraps mod 18.
// af re-read from s_w each call: no weight regs live during staging phases.
template<int BASE>
__device__ __forceinline__ void compute_store(const unsigned char* __restrict__ s_x,
                                              const unsigned char* __restrict__ s_w,
                                              float* __restrict__ out,
                                              int h0, int w0, int wv, int n, int hi) {
    short8 af[9];
    #pragma unroll
    for (int rs = 0; rs < 9; ++rs)
        af[rs] = *(const short8*)(s_w + rs * 1024 + n * 32 + hi * 16);

    #pragma unroll
    for (int t = 0; t < 4; ++t) {
        const int baserow = wv * 4 + t;
        f32x16 acc;
        #pragma unroll
        for (int q = 0; q < 16; ++q) acc[q] = 0.0f;
        #pragma unroll
        for (int r = 0; r < 3; ++r) {
            #pragma unroll
            for (int s = 0; s < 3; ++s) {
                int rr = BASE + baserow + r;
                if (rr >= X_ROWS) rr -= X_ROWS;      // rotating buffer wrap
                const int w   = n + s;
                const int s16 = (hi ^ (w >> 2) ^ (w >> 3)) & 1;
                const int off = rr * ROW_BYTES + w * 32 + s16 * 16;
                const short8 bfr = *(const short8*)(s_x + off);   // ds_read_b128
                acc = __builtin_amdgcn_mfma_f32_32x32x16_bf16(af[r * 3 + s], bfr, acc, 0, 0, 0);
            }
        }
        // C/D: col(lane&31)=pixel, row(q)=(q&3)+8*(q>>2)+4*hi = outch; plain stores
        const int h = h0 + BASE + baserow;
        float* obase = out + (h << 10) + w0 + n;
        #pragma unroll
        for (int q = 0; q < 16; ++q) {
            const int o = (q & 3) + 8 * (q >> 2) + 4 * hi;
            obase[o << 20] = acc[q];
        }
    }
}

__global__ __launch_bounds__(256, 4)
void gck3x3_mfma_kernel(const float* __restrict__ x,
                        const float* __restrict__ kern,
                        float* __restrict__ out) {
    __shared__ __attribute__((aligned(16))) unsigned char s_mem[X_LDS + W_LDS];
    unsigned char* s_x = s_mem;
    unsigned char* s_w = s_mem + X_LDS;

    const int tid  = threadIdx.x;
    const int lane = tid & 63;
    const int wv   = tid >> 6;
    const int n    = lane & 31;
    const int hi   = lane >> 5;

    // XCD-aware bijective swizzle: 1024 = 8*128; vertical neighbors share an XCD L2
    const int bid = blockIdx.x;
    const int swz = (bid & 7) * 128 + (bid >> 3);
    const int h0  = (swz >> 5) * 32;   // 0..992 (block owns 32 output rows)
    const int w0  = (swz & 31) * TW;   // 0..992

    // ---- tile A x-rows h0..h0+17 -> phys 0..17 ----
    stage_tile<18>(x, h0, w0, tid, s_x);

    // ---- weights -> s_w[rs][o][c] bf16 (coalesced; once per block) ----
    {
        float wreg[18];
        #pragma unroll
        for (int k = 0; k < 18; ++k)
            wreg[k] = kern[tid + 256 * k];
        #pragma unroll
        for (int k = 0; k < 18; ++k) {
            const int idx = tid + 256 * k;
            const int o   = idx / 144;
            const int rm  = idx - o * 144;
            const int c   = rm / 9;
            const int rs  = rm - c * 9;
            *(short*)(s_w + rs * 1024 + o * 32 + c * 2) = (short)f2bf(wreg[k]);
        }
    }
    __syncthreads();

    compute_store<0>(s_x, s_w, out, h0, w0, wv, n, hi);     // outputs h0..h0+15
    __syncthreads();   // all waves done reading phys rows 0..15

    // ---- tile B x-rows h0+18..h0+33 -> phys 0..15 (rows 16,17 = x h0+16,17 kept) ----
    // B's global reads overlap A's posted-store drain in the memory system.
    stage_tile<16>(x, h0 + 18, w0, tid, s_x);
    __syncthreads();

    compute_store<16>(s_x, s_w, out, h0, w0, wv, n, hi);    // outputs h0+16..h0+31
}

extern "C" void kernel_launch(void* const* d_in, const int* in_sizes, int n_in,
                              void* d_out, int out_size, void* d_ws, size_t ws_size,
                              hipStream_t stream) {
    (void)in_sizes; (void)n_in; (void)d_ws; (void)ws_size; (void)out_size;
    const float* x    = (const float*)d_in[0];
    const float* kern = (const float*)d_in[1];
    float*       out  = (float*)d_out;
    gck3x3_mfma_kernel<<<1024, 256, 0, stream>>>(x, kern, out);
}